// Round 4
// baseline (362.784 us; speedup 1.0000x reference)
//
#include <hip/hip_runtime.h>
#include <hip/hip_bf16.h>
#include <math.h>

#define LL 96
#define LP 768
#define BD 256
#define HD 128
#define NB 2
#define NEGV (-20.0f)
#define LB 8    // ligands per block
#define PB 16   // proteins per block

#define NBIN 16384   // top-14-bit key histogram
#define BSHIFT 18
#define CAP 8192     // candidate buffer per batch
#define NLOG (LL * LP)

typedef __attribute__((ext_vector_type(4))) float f32x4;
typedef __attribute__((ext_vector_type(4))) unsigned int u32x4;
typedef __attribute__((ext_vector_type(8))) short s16x8;

// Abramowitz-Stegun 7.1.26 erf, |err| <= 1.5e-7 absolute. ~14 VALU ops.
__device__ __forceinline__ float gelu_fast(float x) {
  float ax = fabsf(x) * 0.70710678118654752f;
  float t = 1.0f / fmaf(0.3275911f, ax, 1.0f);
  float poly = t * fmaf(t, fmaf(t, fmaf(t, fmaf(t, 1.061405429f, -1.453152027f),
                                        1.421413741f), -0.284496736f), 0.254829592f);
  float e = __expf(-ax * ax);
  float erfax = fmaf(-poly, e, 1.0f);
  float erfx = copysignf(erfax, x);
  return 0.5f * x * (1.0f + erfx);
}

__device__ __forceinline__ f32x4 mfma16(s16x8 a, s16x8 b, f32x4 c) {
  return __builtin_amdgcn_mfma_f32_16x16x32_bf16(a, b, c, 0, 0, 0);
}

__device__ __forceinline__ unsigned pack_bf16(float a, float b) {
  float2 t; t.x = a; t.y = b;
  __hip_bfloat162 h = __float22bfloat162_rn(t);
  return *reinterpret_cast<unsigned*>(&h);
}

__device__ __forceinline__ unsigned short bfbits(float x) {
  __hip_bfloat16 h = __float2bfloat16(x);
  return *reinterpret_cast<unsigned short*>(&h);
}

__device__ __forceinline__ unsigned int fkey(float f) {
  unsigned int u = __float_as_uint(f);
  return u ^ ((u >> 31) ? 0xFFFFFFFFu : 0x80000000u);
}
__device__ __forceinline__ float finv(unsigned int k) {
  unsigned int u = k ^ ((k >> 31) ? 0x80000000u : 0xFFFFFFFFu);
  return __uint_as_float(u);
}

// ctrl layout (u32): [0,1]=maxkey  [2,3]=binB count  [4,5]=B  [6,7]=G
//                    [8,9]=s1(float) [10,11]=s2(float) [12..15]=pad

// ---------- fused prep: pad decode | weight swizzle | projection chain ------
__global__ __launch_bounds__(256) void prep_kernel(
    const void* lp, const void* pp, unsigned char* lmask, unsigned char* pmask,
    const float* __restrict__ W1, const float* __restrict__ W2,
    unsigned short* __restrict__ W1xf, unsigned short* __restrict__ W2f,
    const float* __restrict__ l_tok, const float* __restrict__ p_tok,
    const float* __restrict__ Wl, const float* __restrict__ bl,
    const float* __restrict__ Wp, const float* __restrict__ bp,
    const float* __restrict__ b1,
    float* __restrict__ wl_, float* __restrict__ wp_,
    float* __restrict__ wA, float* __restrict__ wB) {
  __shared__ float Xs[16 * 256];
  __shared__ float Ys[16 * 256];
  __shared__ int bad;
  const int tid = threadIdx.x;
  if (blockIdx.x == 0) {
    if (tid == 0) bad = 0;
    __syncthreads();
    const unsigned int* li = (const unsigned int*)lp;
    const unsigned int* pi = (const unsigned int*)pp;
    for (int i = tid; i < NB * LL; i += 256) if (li[i] > 1u) atomicOr(&bad, 1);
    for (int i = tid; i < NB * LP; i += 256) if (pi[i] > 1u) atomicOr(&bad, 1);
    __syncthreads();
    const bool asInt = (bad == 0);
    const unsigned char* lb = (const unsigned char*)lp;
    const unsigned char* pb = (const unsigned char*)pp;
    for (int i = tid; i < NB * LL; i += 256)
      lmask[i] = asInt ? (unsigned char)(li[i] != 0u) : (unsigned char)(lb[i] != 0);
    for (int i = tid; i < NB * LP; i += 256)
      pmask[i] = asInt ? (unsigned char)(pi[i] != 0u) : (unsigned char)(pb[i] != 0);
    return;
  }
  if (blockIdx.x < 321) {
    int idx = (blockIdx.x - 1) * 256 + tid;
    if (idx < 65536) {
      int j = idx & 7, ln = (idx >> 3) & 63;
      int rest = idx >> 9;
      int mt = rest & 7, kt = (rest >> 3) & 1, cc = rest >> 4;
      int row = 512 + cc * 64 + kt * 32 + ((ln >> 4) << 3) + j;
      int col = mt * 16 + (ln & 15);
      W1xf[idx] = bfbits(W1[row * HD + col]);
    } else if (idx < 65536 + 16384) {
      int e = idx - 65536;
      int j = e & 7, ln = (e >> 3) & 63, mt = (e >> 9) & 7, kt = e >> 12;
      int row = kt * 32 + ((ln >> 4) << 3) + j;
      int col = mt * 16 + (ln & 15);
      W2f[e] = bfbits(W2[row * HD + col]);
    }
    return;
  }
  // ---- projection chain: X@W+b -> Y1; Y1@W1part(+b1) -> Y2 ----
  const int pblk = blockIdx.x - 321;
  const bool isL = pblk < (NB * LL / 16);
  const int blk = isL ? pblk : (pblk - NB * LL / 16);
  const int r0 = blk * 16;
  const float* X = isL ? l_tok : p_tok;
  const float* W = isL ? Wl : Wp;
  const float* bias = isL ? bl : bp;
  float* Y1 = isL ? wl_ : wp_;
  float* Y2 = isL ? wA : wB;
  const float* W1p = isL ? W1 : (W1 + 256 * HD);

#pragma unroll
  for (int q = 0; q < 16; ++q)
    Xs[tid + q * 256] = X[(size_t)r0 * 256 + tid + q * 256];
  __syncthreads();
  {
    const int cc = tid;
    float bv = bias[cc];
    float acc[16];
#pragma unroll
    for (int i = 0; i < 16; ++i) acc[i] = bv;
    for (int k4 = 0; k4 < 256; k4 += 4) {
      float wv[4];
#pragma unroll
      for (int q = 0; q < 4; ++q) wv[q] = W[(size_t)(k4 + q) * 256 + cc];
#pragma unroll
      for (int i = 0; i < 16; ++i) {
        f32x4 xv = *(const f32x4*)&Xs[i * 256 + k4];
#pragma unroll
        for (int q = 0; q < 4; ++q) acc[i] = fmaf(xv[q], wv[q], acc[i]);
      }
    }
#pragma unroll
    for (int i = 0; i < 16; ++i) {
      Y1[(size_t)(r0 + i) * 256 + cc] = acc[i];
      Ys[i * 256 + cc] = acc[i];
    }
  }
  __syncthreads();
  {
    const int c2 = tid & 127;
    const int half = tid >> 7;
    float bv = isL ? b1[c2] : 0.0f;
    float acc[8];
#pragma unroll
    for (int i = 0; i < 8; ++i) acc[i] = bv;
    for (int k4 = 0; k4 < 256; k4 += 4) {
      float wv[4];
#pragma unroll
      for (int q = 0; q < 4; ++q) wv[q] = W1p[(size_t)(k4 + q) * HD + c2];
#pragma unroll
      for (int i = 0; i < 8; ++i) {
        f32x4 yv = *(const f32x4*)&Ys[(half * 8 + i) * 256 + k4];
#pragma unroll
        for (int q = 0; q < 4; ++q) acc[i] = fmaf(yv[q], wv[q], acc[i]);
      }
    }
#pragma unroll
    for (int i = 0; i < 8; ++i)
      Y2[(size_t)(r0 + half * 8 + i) * HD + c2] = acc[i];
  }
}

// ---------------- MFMA pair kernel (+ fused hist/max) -----------------------
__global__ __launch_bounds__(256, 3) void pair2_kernel(
    const float* __restrict__ lbuf, const float* __restrict__ pbuf,
    const float* __restrict__ A1, const float* __restrict__ B1,
    const unsigned short* __restrict__ W1xf, const unsigned short* __restrict__ W2f,
    const float* __restrict__ b2, const float* __restrict__ W3,
    const float* __restrict__ b3, const unsigned char* __restrict__ lmask,
    const unsigned char* __restrict__ pmask, float* __restrict__ logits,
    unsigned* __restrict__ hist, unsigned* __restrict__ ctrl) {
  __shared__ float ltpt[2][24 * 68];
  __shared__ float U[8192];
  __shared__ float b2s[HD];
  __shared__ float w3s[HD];
  __shared__ float redbuf[128];

  const int tid = threadIdx.x;
  const int lane = tid & 63;
  const int w = tid >> 6;
  const int g = lane >> 4;
  const int c = lane & 15;
  const int wm = w >> 1;
  const int wn = w & 1;
  const int bb = blockIdx.z;
  const int i0 = blockIdx.y * LB;
  const int j0 = blockIdx.x * PB;

  if (tid < 128) b2s[tid] = b2[tid];
  else w3s[tid - 128] = W3[tid - 128];

  const int srow = tid >> 4, sq = tid & 15;
  const int srow2 = (tid + 256) >> 4;

  auto gaddr = [&](int row, int q, int c4) -> const float* {
    return (row < 8)
        ? &lbuf[(size_t)(bb * LL + i0 + row) * BD + c4 * 64 + q * 4]
        : &pbuf[(size_t)(bb * LP + j0 + (row - 8)) * BD + c4 * 64 + q * 4];
  };

  {
    f32x4 r0 = {}, r1 = {};
    if (tid < 384) r0 = *(const f32x4*)gaddr(srow, sq, 0);
    if (tid < 128) r1 = *(const f32x4*)gaddr(srow2, sq, 0);
    if (tid < 384) *(f32x4*)&ltpt[0][srow * 68 + sq * 4] = r0;
    if (tid < 128) *(f32x4*)&ltpt[0][srow2 * 68 + sq * 4] = r1;
  }
  __syncthreads();

  f32x4 acc1[4][4];
#pragma unroll
  for (int m = 0; m < 4; ++m)
#pragma unroll
    for (int n = 0; n < 4; ++n) acc1[m][n] = (f32x4)0.0f;

  const unsigned short* Fush = (const unsigned short*)U;
  unsigned* Fdw = (unsigned*)U;

  for (int c4 = 0; c4 < 4; ++c4) {
    const int buf = c4 & 1;

    s16x8 afr0[2][4];
#pragma unroll
    for (int kt = 0; kt < 2; ++kt)
#pragma unroll
      for (int m = 0; m < 4; ++m)
        afr0[kt][m] = *(const s16x8*)(W1xf +
            ((size_t)((c4 * 2 + kt) * 8 + (wm * 4 + m)) * 64 + lane) * 8);

    f32x4 r0 = {}, r1 = {};
    if (c4 < 3) {
      if (tid < 384) r0 = *(const f32x4*)gaddr(srow, sq, c4 + 1);
      if (tid < 128) r1 = *(const f32x4*)gaddr(srow2, sq, c4 + 1);
    }

#pragma unroll
    for (int f = 0; f < 8; ++f) {
      const int frag = w + f * 4;
      const int t = frag >> 4, kt = (frag >> 3) & 1, ntg = frag & 7;
      const int kc0 = kt * 32 + g * 8;
      const float* lr = &ltpt[buf][ntg * 68 + kc0];
      const float* pr = &ltpt[buf][(8 + c) * 68 + kc0];
      f32x4 l0 = *(const f32x4*)lr;
      f32x4 l1 = *(const f32x4*)(lr + 4);
      f32x4 p0 = *(const f32x4*)pr;
      f32x4 p1 = *(const f32x4*)(pr + 4);
      float x[8];
      if (t == 0) {
#pragma unroll
        for (int q = 0; q < 4; ++q) { x[q] = l0[q] * p0[q]; x[4 + q] = l1[q] * p1[q]; }
      } else {
#pragma unroll
        for (int q = 0; q < 4; ++q) { x[q] = fabsf(l0[q] - p0[q]); x[4 + q] = fabsf(l1[q] - p1[q]); }
      }
      u32x4 pk;
      pk[0] = pack_bf16(x[0], x[1]);
      pk[1] = pack_bf16(x[2], x[3]);
      pk[2] = pack_bf16(x[4], x[5]);
      pk[3] = pack_bf16(x[6], x[7]);
      *(u32x4*)&Fdw[((size_t)frag * 64 + lane) * 4] = pk;
    }

    if (c4 < 3) {
      const int nbuf = buf ^ 1;
      if (tid < 384) *(f32x4*)&ltpt[nbuf][srow * 68 + sq * 4] = r0;
      if (tid < 128) *(f32x4*)&ltpt[nbuf][srow2 * 68 + sq * 4] = r1;
    }
    __syncthreads();

    s16x8 afr1[2][4];
#pragma unroll
    for (int kt = 0; kt < 2; ++kt)
#pragma unroll
      for (int m = 0; m < 4; ++m)
        afr1[kt][m] = *(const s16x8*)(W1xf +
            ((size_t)(((4 + c4) * 2 + kt) * 8 + (wm * 4 + m)) * 64 + lane) * 8);

#pragma unroll
    for (int kt = 0; kt < 2; ++kt)
#pragma unroll
      for (int n = 0; n < 4; ++n) {
        s16x8 bf = *((const s16x8*)Fush + ((kt * 8 + (wn * 4 + n)) * 64 + lane));
#pragma unroll
        for (int m = 0; m < 4; ++m) acc1[m][n] = mfma16(afr0[kt][m], bf, acc1[m][n]);
      }
#pragma unroll
    for (int kt = 0; kt < 2; ++kt)
#pragma unroll
      for (int n = 0; n < 4; ++n) {
        s16x8 bf = *((const s16x8*)Fush + ((16 + kt * 8 + (wn * 4 + n)) * 64 + lane));
#pragma unroll
        for (int m = 0; m < 4; ++m) acc1[m][n] = mfma16(afr1[kt][m], bf, acc1[m][n]);
      }
    __syncthreads();
  }

  unsigned* Hdw = (unsigned*)U;
#pragma unroll
  for (int m = 0; m < 4; ++m) {
    const int hidM = wm * 4 + m;
    const int kt2 = (4 * hidM + g) >> 3;
    const int l2 = ((2 * hidM + (g >> 1)) & 3) * 16 + c;
    const int jd = (g & 1) * 2;
#pragma unroll
    for (int n = 0; n < 4; ++n) {
      const int ntg = wn * 4 + n;
      f32x4 a1v = *(const f32x4*)&A1[(size_t)(bb * LL + i0 + ntg) * HD + hidM * 16 + g * 4];
      f32x4 b1v = *(const f32x4*)&B1[(size_t)(bb * LP + j0 + c) * HD + hidM * 16 + g * 4];
      float h0 = gelu_fast(acc1[m][n][0] + a1v[0] + b1v[0]);
      float h1 = gelu_fast(acc1[m][n][1] + a1v[1] + b1v[1]);
      float h2 = gelu_fast(acc1[m][n][2] + a1v[2] + b1v[2]);
      float h3 = gelu_fast(acc1[m][n][3] + a1v[3] + b1v[3]);
      int base = ((kt2 * 8 + ntg) * 64 + l2) * 4 + jd;
      Hdw[base] = pack_bf16(h0, h1);
      Hdw[base + 1] = pack_bf16(h2, h3);
    }
  }
  __syncthreads();

  f32x4 acc2[4][4];
#pragma unroll
  for (int m = 0; m < 4; ++m)
#pragma unroll
    for (int n = 0; n < 4; ++n) acc2[m][n] = (f32x4)0.0f;

  const unsigned short* Hush = (const unsigned short*)U;
#pragma unroll
  for (int kt = 0; kt < 4; ++kt) {
    s16x8 a2[4];
#pragma unroll
    for (int m = 0; m < 4; ++m)
      a2[m] = *(const s16x8*)(W2f + (size_t)((kt * 8 + (wm * 4 + m)) * 64 + lane) * 8);
#pragma unroll
    for (int n = 0; n < 4; ++n) {
      s16x8 bf = *((const s16x8*)Hush + ((kt * 8 + (wn * 4 + n)) * 64 + lane));
#pragma unroll
      for (int m = 0; m < 4; ++m) acc2[m][n] = mfma16(a2[m], bf, acc2[m][n]);
    }
  }

  float partial[4] = {0.0f, 0.0f, 0.0f, 0.0f};
#pragma unroll
  for (int m = 0; m < 4; ++m) {
    const int hb = (wm * 4 + m) * 16 + g * 4;
    f32x4 b2v = *(const f32x4*)&b2s[hb];
    f32x4 w3v = *(const f32x4*)&w3s[hb];
#pragma unroll
    for (int n = 0; n < 4; ++n) {
#pragma unroll
      for (int r = 0; r < 4; ++r)
        partial[n] = fmaf(gelu_fast(acc2[m][n][r] + b2v[r]), w3v[r], partial[n]);
    }
  }
#pragma unroll
  for (int n = 0; n < 4; ++n) {
    partial[n] += __shfl_xor(partial[n], 16, 64);
    partial[n] += __shfl_xor(partial[n], 32, 64);
  }
  if (wm == 0 && g == 0) {
#pragma unroll
    for (int n = 0; n < 4; ++n) redbuf[wn * 64 + n * 16 + c] = partial[n];
  }
  __syncthreads();
  if (wm == 1 && g == 0) {
    const float bb3 = b3[0];
#pragma unroll
    for (int n = 0; n < 4; ++n) {
      const int ntg = wn * 4 + n;
      float v = partial[n] + redbuf[wn * 64 + n * 16 + c] + bb3;
      if (isnan(v)) v = 0.0f;
      else if (isinf(v)) v = (v > 0.0f) ? 20.0f : NEGV;
      const int i = i0 + ntg, j = j0 + c;
      if (lmask[bb * LL + i] || pmask[bb * LP + j]) v = NEGV;
      logits[(size_t)bb * NLOG + i * LP + j] = v;
      unsigned k = fkey(v);
      atomicMax(&ctrl[bb], k);
      atomicAdd(&hist[bb * NBIN + (k >> BSHIFT)], 1u);
    }
  }
}

// ---------------- find bin containing the 100th largest ---------------------
__global__ __launch_bounds__(256) void findbin_kernel(const unsigned* __restrict__ hist,
                                                      unsigned* __restrict__ ctrl) {
  __shared__ unsigned csum[256];
  __shared__ unsigned suf[256];
  const int tid = threadIdx.x;
  for (int b = 0; b < NB; ++b) {
    const unsigned* h = hist + b * NBIN;
    const int base = tid * (NBIN / 256);
    unsigned s = 0;
    for (int i = 0; i < NBIN / 256; ++i) s += h[base + i];
    csum[tid] = s;
    __syncthreads();
    if (tid == 0) {
      unsigned a = 0;
      for (int t = 255; t >= 0; --t) { suf[t] = a; a += csum[t]; }
    }
    __syncthreads();
    unsigned above = suf[tid];
    if (above < 100u && above + csum[tid] >= 100u) {
      unsigned a = above;
      for (int i = NBIN / 256 - 1; i >= 0; --i) {
        unsigned hc = h[base + i];
        if (a + hc >= 100u) { ctrl[4 + b] = base + i; ctrl[6 + b] = a; break; }
        a += hc;
      }
    }
    __syncthreads();
  }
}

// ---------------- parallel pass: sums above bin B + collect bin-B candidates
__global__ __launch_bounds__(256) void sums_kernel(const float* __restrict__ logits,
                                                   unsigned* __restrict__ ctrl,
                                                   float* __restrict__ cand) {
  const int b = blockIdx.y;
  const float* data = logits + (size_t)b * NLOG;
  const unsigned B = ctrl[4 + b];
  const float vmax = finv(ctrl[b]);
  float* s1 = (float*)&ctrl[8 + b];
  float* s2 = (float*)&ctrl[10 + b];
  const int stride = gridDim.x * 256;
  float l1 = 0.0f, l2 = 0.0f;
  for (int i = blockIdx.x * 256 + threadIdx.x; i < NLOG; i += stride) {
    float v = data[i];
    unsigned k16 = fkey(v) >> BSHIFT;
    if (k16 > B) {
      float e = __expf(v - vmax);
      l1 += e;
      l2 = fmaf(e, v, l2);
    } else if (k16 == B) {
      unsigned pos = atomicAdd(&ctrl[2 + b], 1u);
      if (pos < CAP) cand[(size_t)b * CAP + pos] = v;
    }
  }
  if (l1 != 0.0f) { atomicAdd(s1, l1); atomicAdd(s2, l2); }
}

// ---------------- exact select among candidates + combine -------------------
__global__ __launch_bounds__(256) void final_kernel(const float* __restrict__ logits,
                                                    const unsigned* __restrict__ ctrl,
                                                    const float* __restrict__ cand,
                                                    float* __restrict__ out) {
  __shared__ float cv[CAP];
  __shared__ unsigned h8[256];
  __shared__ float red[256];
  __shared__ unsigned sP, sN;
  const int b = blockIdx.x;
  const int tid = threadIdx.x;
  const unsigned count = ctrl[2 + b];
  const float vmax = finv(ctrl[b]);
  const unsigned G = ctrl[6 + b];
  const float s1g = ((const float*)ctrl)[8 + b];
  const float s2g = ((const float*)ctrl)[10 + b];
  const float* data = logits + (size_t)b * NLOG;
  const bool fb = count > CAP;  // degenerate fallback: full-array select
  const unsigned C = fb ? 0u : count;

  if (!fb) for (int i = tid; i < (int)C; i += 256) cv[i] = cand[(size_t)b * CAP + i];
  if (tid == 0) { sP = 0u; sN = fb ? 100u : (100u - G); }
  __syncthreads();

  for (int sh = 24; sh >= 0; sh -= 8) {
    h8[tid] = 0u;
    __syncthreads();
    const unsigned prefix = sP;
    const unsigned maskhi = (sh == 24) ? 0u : (0xFFFFFFFFu << (sh + 8));
    if (!fb) {
      for (int i = tid; i < (int)C; i += 256) {
        unsigned k = fkey(cv[i]);
        if ((k & maskhi) == (prefix & maskhi)) atomicAdd(&h8[(k >> sh) & 255], 1u);
      }
    } else {
      for (int i = tid; i < NLOG; i += 256) {
        unsigned k = fkey(data[i]);
        if ((k & maskhi) == (prefix & maskhi)) atomicAdd(&h8[(k >> sh) & 255], 1u);
      }
    }
    __syncthreads();
    if (tid == 0) {
      unsigned need = sN, cum = 0u;
      int d = 0;
      for (d = 255; d >= 0; --d) { cum += h8[d]; if (cum >= need) break; }
      sN = need - (cum - h8[d]);
      sP = prefix | ((unsigned)d << sh);
    }
    __syncthreads();
  }
  const unsigned Tkey = sP;
  const unsigned nT = sN;
  const float T = finv(Tkey);

  float l1 = 0.0f, l2 = 0.0f;
  if (!fb) {
    for (int i = tid; i < (int)C; i += 256) {
      float v = cv[i];
      if (fkey(v) > Tkey) { float e = __expf(v - vmax); l1 += e; l2 = fmaf(e, v, l2); }
    }
  } else {
    for (int i = tid; i < NLOG; i += 256) {
      float v = data[i];
      if (fkey(v) > Tkey) { float e = __expf(v - vmax); l1 += e; l2 = fmaf(e, v, l2); }
    }
  }
  red[tid] = l1;
  __syncthreads();
  for (int s = 128; s > 0; s >>= 1) { if (tid < s) red[tid] += red[tid + s]; __syncthreads(); }
  const float s1c = red[0];
  __syncthreads();
  red[tid] = l2;
  __syncthreads();
  for (int s = 128; s > 0; s >>= 1) { if (tid < s) red[tid] += red[tid + s]; __syncthreads(); }
  if (tid == 0) {
    const float s2c = red[0];
    const float e = __expf(T - vmax);
    const float g1 = fb ? 0.0f : s1g;
    const float g2 = fb ? 0.0f : s2g;
    const float denom = g1 + s1c + (float)nT * e;
    const float num = g2 + s2c + (float)nT * e * T;
    out[b] = num / denom;
  }
}

// ---------------------------------------------------------------------------
extern "C" void kernel_launch(void* const* d_in, const int* in_sizes, int n_in,
                              void* d_out, int out_size, void* d_ws, size_t ws_size,
                              hipStream_t stream) {
  const float* l_tok = (const float*)d_in[0];
  const float* p_tok = (const float*)d_in[1];
  const void* l_pad = d_in[2];
  const void* p_pad = d_in[3];
  const float* Wl = (const float*)d_in[4];
  const float* bl = (const float*)d_in[5];
  const float* Wp = (const float*)d_in[6];
  const float* bp = (const float*)d_in[7];
  const float* W1 = (const float*)d_in[8];
  const float* b1 = (const float*)d_in[9];
  const float* W2 = (const float*)d_in[10];
  const float* b2 = (const float*)d_in[11];
  const float* W3 = (const float*)d_in[12];
  const float* b3 = (const float*)d_in[13];

  float* ws = (float*)d_ws;
  float* wl_ = ws;                    // [2,96,256]
  float* wp_ = ws + 49152;            // [2,768,256]
  float* wA = ws + 442368;            // A1 [2,96,128]
  float* wB = ws + 466944;            // B1 [2,768,128]
  float* wLog = ws + 663552;          // logits [2,73728]
  unsigned char* lmask = (unsigned char*)(ws + 811008);
  unsigned char* pmask = lmask + NB * LL;
  unsigned short* W1xf = (unsigned short*)(ws + 811520);  // 65536 u16
  unsigned short* W2f = (unsigned short*)(ws + 844288);   // 16384 u16
  unsigned* hist = (unsigned*)(ws + 852480);              // [2][NBIN] u32
  unsigned* ctrl = (unsigned*)(ws + 852480 + NB * NBIN);  // 16 u32
  float* cand = ws + 852480 + NB * NBIN + 16;             // [2][CAP]

  // zero hist + ctrl each launch (graph-safe)
  hipMemsetAsync((void*)hist, 0, (NB * NBIN + 16) * sizeof(unsigned), stream);

  prep_kernel<<<321 + NB * (LL + LP) / 16, 256, 0, stream>>>(
      l_pad, p_pad, lmask, pmask, W1, W2, W1xf, W2f,
      l_tok, p_tok, Wl, bl, Wp, bp, b1, wl_, wp_, wA, wB);

  dim3 grid(LP / PB, LL / LB, NB);
  pair2_kernel<<<grid, 256, 0, stream>>>(wl_, wp_, wA, wB, W1xf, W2f,
                                         b2, W3, b3, lmask, pmask, wLog,
                                         hist, ctrl);
  findbin_kernel<<<1, 256, 0, stream>>>(hist, ctrl);
  sums_kernel<<<dim3(32, NB), 256, 0, stream>>>(wLog, ctrl, cand);
  final_kernel<<<NB, 256, 0, stream>>>(wLog, ctrl, cand, (float*)d_out);
}

// Round 5
// 197.376 us; speedup vs baseline: 1.8380x; 1.8380x over previous
//
#include <hip/hip_runtime.h>
#include <hip/hip_bf16.h>
#include <math.h>

#define LL 96
#define LP 768
#define BD 256
#define HD 128
#define NB 2
#define NEGV (-20.0f)
#define LB 8    // ligands per block
#define PB 16   // proteins per block

#define NBIN 4096    // top-12-bit key histogram (sign+exp+3 mantissa bits)
#define BSHIFT 20
#define CAP 8192     // candidate buffer per batch
#define NLOG (LL * LP)

typedef __attribute__((ext_vector_type(4))) float f32x4;
typedef __attribute__((ext_vector_type(4))) unsigned int u32x4;
typedef __attribute__((ext_vector_type(8))) short s16x8;

// Abramowitz-Stegun 7.1.26 erf, |err| <= 1.5e-7 absolute. ~14 VALU ops.
__device__ __forceinline__ float gelu_fast(float x) {
  float ax = fabsf(x) * 0.70710678118654752f;
  float t = 1.0f / fmaf(0.3275911f, ax, 1.0f);
  float poly = t * fmaf(t, fmaf(t, fmaf(t, fmaf(t, 1.061405429f, -1.453152027f),
                                        1.421413741f), -0.284496736f), 0.254829592f);
  float e = __expf(-ax * ax);
  float erfax = fmaf(-poly, e, 1.0f);
  float erfx = copysignf(erfax, x);
  return 0.5f * x * (1.0f + erfx);
}

__device__ __forceinline__ f32x4 mfma16(s16x8 a, s16x8 b, f32x4 c) {
  return __builtin_amdgcn_mfma_f32_16x16x32_bf16(a, b, c, 0, 0, 0);
}

__device__ __forceinline__ unsigned pack_bf16(float a, float b) {
  float2 t; t.x = a; t.y = b;
  __hip_bfloat162 h = __float22bfloat162_rn(t);
  return *reinterpret_cast<unsigned*>(&h);
}

__device__ __forceinline__ unsigned short bfbits(float x) {
  __hip_bfloat16 h = __float2bfloat16(x);
  return *reinterpret_cast<unsigned short*>(&h);
}

__device__ __forceinline__ unsigned int fkey(float f) {
  unsigned int u = __float_as_uint(f);
  return u ^ ((u >> 31) ? 0xFFFFFFFFu : 0x80000000u);
}
__device__ __forceinline__ float finv(unsigned int k) {
  unsigned int u = k ^ ((k >> 31) ? 0x80000000u : 0xFFFFFFFFu);
  return __uint_as_float(u);
}

// ctrl layout (u32): [0,1]=ubkey (>= max)  [2,3]=binB count  [4,5]=B  [6,7]=G
//                    [8,9]=s1(float) [10,11]=s2(float) [12..15]=pad

// ---------- fused prep: pad decode | weight swizzle | projection chain ------
__global__ __launch_bounds__(256) void prep_kernel(
    const void* lp, const void* pp, unsigned char* lmask, unsigned char* pmask,
    const float* __restrict__ W1, const float* __restrict__ W2,
    unsigned short* __restrict__ W1xf, unsigned short* __restrict__ W2f,
    const float* __restrict__ l_tok, const float* __restrict__ p_tok,
    const float* __restrict__ Wl, const float* __restrict__ bl,
    const float* __restrict__ Wp, const float* __restrict__ bp,
    const float* __restrict__ b1,
    float* __restrict__ wl_, float* __restrict__ wp_,
    float* __restrict__ wA, float* __restrict__ wB) {
  __shared__ float Xs[16 * 256];
  __shared__ float Ys[16 * 256];
  __shared__ int bad;
  const int tid = threadIdx.x;
  if (blockIdx.x == 0) {
    if (tid == 0) bad = 0;
    __syncthreads();
    const unsigned int* li = (const unsigned int*)lp;
    const unsigned int* pi = (const unsigned int*)pp;
    for (int i = tid; i < NB * LL; i += 256) if (li[i] > 1u) atomicOr(&bad, 1);
    for (int i = tid; i < NB * LP; i += 256) if (pi[i] > 1u) atomicOr(&bad, 1);
    __syncthreads();
    const bool asInt = (bad == 0);
    const unsigned char* lb = (const unsigned char*)lp;
    const unsigned char* pb = (const unsigned char*)pp;
    for (int i = tid; i < NB * LL; i += 256)
      lmask[i] = asInt ? (unsigned char)(li[i] != 0u) : (unsigned char)(lb[i] != 0);
    for (int i = tid; i < NB * LP; i += 256)
      pmask[i] = asInt ? (unsigned char)(pi[i] != 0u) : (unsigned char)(pb[i] != 0);
    return;
  }
  if (blockIdx.x < 321) {
    int idx = (blockIdx.x - 1) * 256 + tid;
    if (idx < 65536) {
      int j = idx & 7, ln = (idx >> 3) & 63;
      int rest = idx >> 9;
      int mt = rest & 7, kt = (rest >> 3) & 1, cc = rest >> 4;
      int row = 512 + cc * 64 + kt * 32 + ((ln >> 4) << 3) + j;
      int col = mt * 16 + (ln & 15);
      W1xf[idx] = bfbits(W1[row * HD + col]);
    } else if (idx < 65536 + 16384) {
      int e = idx - 65536;
      int j = e & 7, ln = (e >> 3) & 63, mt = (e >> 9) & 7, kt = e >> 12;
      int row = kt * 32 + ((ln >> 4) << 3) + j;
      int col = mt * 16 + (ln & 15);
      W2f[e] = bfbits(W2[row * HD + col]);
    }
    return;
  }
  // ---- projection chain: X@W+b -> Y1; Y1@W1part(+b1) -> Y2 ----
  const int pblk = blockIdx.x - 321;
  const bool isL = pblk < (NB * LL / 16);
  const int blk = isL ? pblk : (pblk - NB * LL / 16);
  const int r0 = blk * 16;
  const float* X = isL ? l_tok : p_tok;
  const float* W = isL ? Wl : Wp;
  const float* bias = isL ? bl : bp;
  float* Y1 = isL ? wl_ : wp_;
  float* Y2 = isL ? wA : wB;
  const float* W1p = isL ? W1 : (W1 + 256 * HD);

#pragma unroll
  for (int q = 0; q < 16; ++q)
    Xs[tid + q * 256] = X[(size_t)r0 * 256 + tid + q * 256];
  __syncthreads();
  {
    const int cc = tid;
    float bv = bias[cc];
    float acc[16];
#pragma unroll
    for (int i = 0; i < 16; ++i) acc[i] = bv;
    for (int k4 = 0; k4 < 256; k4 += 4) {
      float wv[4];
#pragma unroll
      for (int q = 0; q < 4; ++q) wv[q] = W[(size_t)(k4 + q) * 256 + cc];
#pragma unroll
      for (int i = 0; i < 16; ++i) {
        f32x4 xv = *(const f32x4*)&Xs[i * 256 + k4];
#pragma unroll
        for (int q = 0; q < 4; ++q) acc[i] = fmaf(xv[q], wv[q], acc[i]);
      }
    }
#pragma unroll
    for (int i = 0; i < 16; ++i) {
      Y1[(size_t)(r0 + i) * 256 + cc] = acc[i];
      Ys[i * 256 + cc] = acc[i];
    }
  }
  __syncthreads();
  {
    const int c2 = tid & 127;
    const int half = tid >> 7;
    float bv = isL ? b1[c2] : 0.0f;
    float acc[8];
#pragma unroll
    for (int i = 0; i < 8; ++i) acc[i] = bv;
    for (int k4 = 0; k4 < 256; k4 += 4) {
      float wv[4];
#pragma unroll
      for (int q = 0; q < 4; ++q) wv[q] = W1p[(size_t)(k4 + q) * HD + c2];
#pragma unroll
      for (int i = 0; i < 8; ++i) {
        f32x4 yv = *(const f32x4*)&Ys[(half * 8 + i) * 256 + k4];
#pragma unroll
        for (int q = 0; q < 4; ++q) acc[i] = fmaf(yv[q], wv[q], acc[i]);
      }
    }
#pragma unroll
    for (int i = 0; i < 8; ++i)
      Y2[(size_t)(r0 + half * 8 + i) * HD + c2] = acc[i];
  }
}

// ---------------- MFMA pair kernel (round-3 body: NO atomics) ---------------
__global__ __launch_bounds__(256, 3) void pair2_kernel(
    const float* __restrict__ lbuf, const float* __restrict__ pbuf,
    const float* __restrict__ A1, const float* __restrict__ B1,
    const unsigned short* __restrict__ W1xf, const unsigned short* __restrict__ W2f,
    const float* __restrict__ b2, const float* __restrict__ W3,
    const float* __restrict__ b3, const unsigned char* __restrict__ lmask,
    const unsigned char* __restrict__ pmask, float* __restrict__ logits) {
  __shared__ float ltpt[2][24 * 68];
  __shared__ float U[8192];
  __shared__ float b2s[HD];
  __shared__ float w3s[HD];
  __shared__ float redbuf[128];

  const int tid = threadIdx.x;
  const int lane = tid & 63;
  const int w = tid >> 6;
  const int g = lane >> 4;
  const int c = lane & 15;
  const int wm = w >> 1;
  const int wn = w & 1;
  const int bb = blockIdx.z;
  const int i0 = blockIdx.y * LB;
  const int j0 = blockIdx.x * PB;

  if (tid < 128) b2s[tid] = b2[tid];
  else w3s[tid - 128] = W3[tid - 128];

  const int srow = tid >> 4, sq = tid & 15;
  const int srow2 = (tid + 256) >> 4;

  auto gaddr = [&](int row, int q, int c4) -> const float* {
    return (row < 8)
        ? &lbuf[(size_t)(bb * LL + i0 + row) * BD + c4 * 64 + q * 4]
        : &pbuf[(size_t)(bb * LP + j0 + (row - 8)) * BD + c4 * 64 + q * 4];
  };

  {
    f32x4 r0 = {}, r1 = {};
    if (tid < 384) r0 = *(const f32x4*)gaddr(srow, sq, 0);
    if (tid < 128) r1 = *(const f32x4*)gaddr(srow2, sq, 0);
    if (tid < 384) *(f32x4*)&ltpt[0][srow * 68 + sq * 4] = r0;
    if (tid < 128) *(f32x4*)&ltpt[0][srow2 * 68 + sq * 4] = r1;
  }
  __syncthreads();

  f32x4 acc1[4][4];
#pragma unroll
  for (int m = 0; m < 4; ++m)
#pragma unroll
    for (int n = 0; n < 4; ++n) acc1[m][n] = (f32x4)0.0f;

  const unsigned short* Fush = (const unsigned short*)U;
  unsigned* Fdw = (unsigned*)U;

  for (int c4 = 0; c4 < 4; ++c4) {
    const int buf = c4 & 1;

    s16x8 afr0[2][4];
#pragma unroll
    for (int kt = 0; kt < 2; ++kt)
#pragma unroll
      for (int m = 0; m < 4; ++m)
        afr0[kt][m] = *(const s16x8*)(W1xf +
            ((size_t)((c4 * 2 + kt) * 8 + (wm * 4 + m)) * 64 + lane) * 8);

    f32x4 r0 = {}, r1 = {};
    if (c4 < 3) {
      if (tid < 384) r0 = *(const f32x4*)gaddr(srow, sq, c4 + 1);
      if (tid < 128) r1 = *(const f32x4*)gaddr(srow2, sq, c4 + 1);
    }

#pragma unroll
    for (int f = 0; f < 8; ++f) {
      const int frag = w + f * 4;
      const int t = frag >> 4, kt = (frag >> 3) & 1, ntg = frag & 7;
      const int kc0 = kt * 32 + g * 8;
      const float* lr = &ltpt[buf][ntg * 68 + kc0];
      const float* pr = &ltpt[buf][(8 + c) * 68 + kc0];
      f32x4 l0 = *(const f32x4*)lr;
      f32x4 l1 = *(const f32x4*)(lr + 4);
      f32x4 p0 = *(const f32x4*)pr;
      f32x4 p1 = *(const f32x4*)(pr + 4);
      float x[8];
      if (t == 0) {
#pragma unroll
        for (int q = 0; q < 4; ++q) { x[q] = l0[q] * p0[q]; x[4 + q] = l1[q] * p1[q]; }
      } else {
#pragma unroll
        for (int q = 0; q < 4; ++q) { x[q] = fabsf(l0[q] - p0[q]); x[4 + q] = fabsf(l1[q] - p1[q]); }
      }
      u32x4 pk;
      pk[0] = pack_bf16(x[0], x[1]);
      pk[1] = pack_bf16(x[2], x[3]);
      pk[2] = pack_bf16(x[4], x[5]);
      pk[3] = pack_bf16(x[6], x[7]);
      *(u32x4*)&Fdw[((size_t)frag * 64 + lane) * 4] = pk;
    }

    if (c4 < 3) {
      const int nbuf = buf ^ 1;
      if (tid < 384) *(f32x4*)&ltpt[nbuf][srow * 68 + sq * 4] = r0;
      if (tid < 128) *(f32x4*)&ltpt[nbuf][srow2 * 68 + sq * 4] = r1;
    }
    __syncthreads();

    s16x8 afr1[2][4];
#pragma unroll
    for (int kt = 0; kt < 2; ++kt)
#pragma unroll
      for (int m = 0; m < 4; ++m)
        afr1[kt][m] = *(const s16x8*)(W1xf +
            ((size_t)(((4 + c4) * 2 + kt) * 8 + (wm * 4 + m)) * 64 + lane) * 8);

#pragma unroll
    for (int kt = 0; kt < 2; ++kt)
#pragma unroll
      for (int n = 0; n < 4; ++n) {
        s16x8 bf = *((const s16x8*)Fush + ((kt * 8 + (wn * 4 + n)) * 64 + lane));
#pragma unroll
        for (int m = 0; m < 4; ++m) acc1[m][n] = mfma16(afr0[kt][m], bf, acc1[m][n]);
      }
#pragma unroll
    for (int kt = 0; kt < 2; ++kt)
#pragma unroll
      for (int n = 0; n < 4; ++n) {
        s16x8 bf = *((const s16x8*)Fush + ((16 + kt * 8 + (wn * 4 + n)) * 64 + lane));
#pragma unroll
        for (int m = 0; m < 4; ++m) acc1[m][n] = mfma16(afr1[kt][m], bf, acc1[m][n]);
      }
    __syncthreads();
  }

  unsigned* Hdw = (unsigned*)U;
#pragma unroll
  for (int m = 0; m < 4; ++m) {
    const int hidM = wm * 4 + m;
    const int kt2 = (4 * hidM + g) >> 3;
    const int l2 = ((2 * hidM + (g >> 1)) & 3) * 16 + c;
    const int jd = (g & 1) * 2;
#pragma unroll
    for (int n = 0; n < 4; ++n) {
      const int ntg = wn * 4 + n;
      f32x4 a1v = *(const f32x4*)&A1[(size_t)(bb * LL + i0 + ntg) * HD + hidM * 16 + g * 4];
      f32x4 b1v = *(const f32x4*)&B1[(size_t)(bb * LP + j0 + c) * HD + hidM * 16 + g * 4];
      float h0 = gelu_fast(acc1[m][n][0] + a1v[0] + b1v[0]);
      float h1 = gelu_fast(acc1[m][n][1] + a1v[1] + b1v[1]);
      float h2 = gelu_fast(acc1[m][n][2] + a1v[2] + b1v[2]);
      float h3 = gelu_fast(acc1[m][n][3] + a1v[3] + b1v[3]);
      int base = ((kt2 * 8 + ntg) * 64 + l2) * 4 + jd;
      Hdw[base] = pack_bf16(h0, h1);
      Hdw[base + 1] = pack_bf16(h2, h3);
    }
  }
  __syncthreads();

  f32x4 acc2[4][4];
#pragma unroll
  for (int m = 0; m < 4; ++m)
#pragma unroll
    for (int n = 0; n < 4; ++n) acc2[m][n] = (f32x4)0.0f;

  const unsigned short* Hush = (const unsigned short*)U;
#pragma unroll
  for (int kt = 0; kt < 4; ++kt) {
    s16x8 a2[4];
#pragma unroll
    for (int m = 0; m < 4; ++m)
      a2[m] = *(const s16x8*)(W2f + (size_t)((kt * 8 + (wm * 4 + m)) * 64 + lane) * 8);
#pragma unroll
    for (int n = 0; n < 4; ++n) {
      s16x8 bf = *((const s16x8*)Hush + ((kt * 8 + (wn * 4 + n)) * 64 + lane));
#pragma unroll
      for (int m = 0; m < 4; ++m) acc2[m][n] = mfma16(a2[m], bf, acc2[m][n]);
    }
  }

  float partial[4] = {0.0f, 0.0f, 0.0f, 0.0f};
#pragma unroll
  for (int m = 0; m < 4; ++m) {
    const int hb = (wm * 4 + m) * 16 + g * 4;
    f32x4 b2v = *(const f32x4*)&b2s[hb];
    f32x4 w3v = *(const f32x4*)&w3s[hb];
#pragma unroll
    for (int n = 0; n < 4; ++n) {
#pragma unroll
      for (int r = 0; r < 4; ++r)
        partial[n] = fmaf(gelu_fast(acc2[m][n][r] + b2v[r]), w3v[r], partial[n]);
    }
  }
#pragma unroll
  for (int n = 0; n < 4; ++n) {
    partial[n] += __shfl_xor(partial[n], 16, 64);
    partial[n] += __shfl_xor(partial[n], 32, 64);
  }
  if (wm == 0 && g == 0) {
#pragma unroll
    for (int n = 0; n < 4; ++n) redbuf[wn * 64 + n * 16 + c] = partial[n];
  }
  __syncthreads();
  if (wm == 1 && g == 0) {
    const float bb3 = b3[0];
#pragma unroll
    for (int n = 0; n < 4; ++n) {
      const int ntg = wn * 4 + n;
      float v = partial[n] + redbuf[wn * 64 + n * 16 + c] + bb3;
      if (isnan(v)) v = 0.0f;
      else if (isinf(v)) v = (v > 0.0f) ? 20.0f : NEGV;
      const int i = i0 + ntg, j = j0 + c;
      if (lmask[bb * LL + i] || pmask[bb * LP + j]) v = NEGV;
      logits[(size_t)bb * NLOG + i * LP + j] = v;
    }
  }
}

// ---------------- per-block LDS histogram over logit keys -------------------
__global__ __launch_bounds__(256) void hist_kernel(const float* __restrict__ logits,
                                                   unsigned* __restrict__ hist) {
  __shared__ unsigned lh[NBIN];
  const int b = blockIdx.y;
  const int tid = threadIdx.x;
  for (int i = tid; i < NBIN; i += 256) lh[i] = 0u;
  __syncthreads();
  const float* data = logits + (size_t)b * NLOG;
  const int stride = gridDim.x * 256;
  for (int i = blockIdx.x * 256 + tid; i < NLOG; i += stride)
    atomicAdd(&lh[fkey(data[i]) >> BSHIFT], 1u);
  __syncthreads();
  unsigned* gh = hist + b * NBIN;
  for (int i = tid; i < NBIN; i += 256) {
    unsigned v = lh[i];
    if (v) atomicAdd(&gh[i], v);
  }
}

// ------- find bin of the 100th largest + upper bound on max (no atomics) ----
__global__ __launch_bounds__(256) void findbin_kernel(const unsigned* __restrict__ hist,
                                                      unsigned* __restrict__ ctrl) {
  __shared__ unsigned csum[256];
  __shared__ unsigned suf[256];
  __shared__ unsigned topb[256];
  const int tid = threadIdx.x;
  for (int b = 0; b < NB; ++b) {
    const unsigned* h = hist + b * NBIN;
    const int base = tid * (NBIN / 256);
    unsigned s = 0;
    int top = -1;
    for (int i = 0; i < NBIN / 256; ++i) {
      unsigned cnt = h[base + i];
      s += cnt;
      if (cnt) top = base + i;
    }
    csum[tid] = s;
    topb[tid] = (unsigned)(top + 1);
    __syncthreads();
    if (tid == 0) {
      unsigned a = 0;
      for (int t = 255; t >= 0; --t) { suf[t] = a; a += csum[t]; }
      unsigned mt = 0;
      for (int t = 0; t < 256; ++t) mt = max(mt, topb[t]);
      // key upper bound >= true max (bin upper edge of the top nonempty bin)
      ctrl[b] = ((mt - 1u) << BSHIFT) | ((1u << BSHIFT) - 1u);
    }
    __syncthreads();
    unsigned above = suf[tid];
    if (above < 100u && above + csum[tid] >= 100u) {
      unsigned a = above;
      for (int i = NBIN / 256 - 1; i >= 0; --i) {
        unsigned hc = h[base + i];
        if (a + hc >= 100u) { ctrl[4 + b] = base + i; ctrl[6 + b] = a; break; }
        a += hc;
      }
    }
    __syncthreads();
  }
}

// ---------------- parallel pass: sums above bin B + collect bin-B candidates
__global__ __launch_bounds__(256) void sums_kernel(const float* __restrict__ logits,
                                                   unsigned* __restrict__ ctrl,
                                                   float* __restrict__ cand) {
  const int b = blockIdx.y;
  const float* data = logits + (size_t)b * NLOG;
  const unsigned B = ctrl[4 + b];
  const float vmax = finv(ctrl[b]);
  float* s1 = (float*)&ctrl[8 + b];
  float* s2 = (float*)&ctrl[10 + b];
  const int stride = gridDim.x * 256;
  float l1 = 0.0f, l2 = 0.0f;
  for (int i = blockIdx.x * 256 + threadIdx.x; i < NLOG; i += stride) {
    float v = data[i];
    unsigned kb = fkey(v) >> BSHIFT;
    if (kb > B) {
      float e = __expf(v - vmax);
      l1 += e;
      l2 = fmaf(e, v, l2);
    } else if (kb == B) {
      unsigned pos = atomicAdd(&ctrl[2 + b], 1u);
      if (pos < CAP) cand[(size_t)b * CAP + pos] = v;
    }
  }
  if (l1 != 0.0f) { atomicAdd(s1, l1); atomicAdd(s2, l2); }
}

// ---------------- exact select among candidates + combine -------------------
__global__ __launch_bounds__(256) void final_kernel(const float* __restrict__ logits,
                                                    const unsigned* __restrict__ ctrl,
                                                    const float* __restrict__ cand,
                                                    float* __restrict__ out) {
  __shared__ float cv[CAP];
  __shared__ unsigned h8[256];
  __shared__ float red[256];
  __shared__ unsigned sP, sN;
  const int b = blockIdx.x;
  const int tid = threadIdx.x;
  const unsigned count = ctrl[2 + b];
  const float vmax = finv(ctrl[b]);
  const unsigned G = ctrl[6 + b];
  const float s1g = ((const float*)ctrl)[8 + b];
  const float s2g = ((const float*)ctrl)[10 + b];
  const float* data = logits + (size_t)b * NLOG;
  const bool fb = count > CAP;  // degenerate fallback: full-array select
  const unsigned C = fb ? 0u : count;

  if (!fb) for (int i = tid; i < (int)C; i += 256) cv[i] = cand[(size_t)b * CAP + i];
  if (tid == 0) { sP = 0u; sN = fb ? 100u : (100u - G); }
  __syncthreads();

  for (int sh = 24; sh >= 0; sh -= 8) {
    h8[tid] = 0u;
    __syncthreads();
    const unsigned prefix = sP;
    const unsigned maskhi = (sh == 24) ? 0u : (0xFFFFFFFFu << (sh + 8));
    if (!fb) {
      for (int i = tid; i < (int)C; i += 256) {
        unsigned k = fkey(cv[i]);
        if ((k & maskhi) == (prefix & maskhi)) atomicAdd(&h8[(k >> sh) & 255], 1u);
      }
    } else {
      for (int i = tid; i < NLOG; i += 256) {
        unsigned k = fkey(data[i]);
        if ((k & maskhi) == (prefix & maskhi)) atomicAdd(&h8[(k >> sh) & 255], 1u);
      }
    }
    __syncthreads();
    if (tid == 0) {
      unsigned need = sN, cum = 0u;
      int d = 0;
      for (d = 255; d >= 0; --d) { cum += h8[d]; if (cum >= need) break; }
      sN = need - (cum - h8[d]);
      sP = prefix | ((unsigned)d << sh);
    }
    __syncthreads();
  }
  const unsigned Tkey = sP;
  const unsigned nT = sN;
  const float T = finv(Tkey);

  float l1 = 0.0f, l2 = 0.0f;
  if (!fb) {
    for (int i = tid; i < (int)C; i += 256) {
      float v = cv[i];
      if (fkey(v) > Tkey) { float e = __expf(v - vmax); l1 += e; l2 = fmaf(e, v, l2); }
    }
  } else {
    for (int i = tid; i < NLOG; i += 256) {
      float v = data[i];
      if (fkey(v) > Tkey) { float e = __expf(v - vmax); l1 += e; l2 = fmaf(e, v, l2); }
    }
  }
  red[tid] = l1;
  __syncthreads();
  for (int s = 128; s > 0; s >>= 1) { if (tid < s) red[tid] += red[tid + s]; __syncthreads(); }
  const float s1c = red[0];
  __syncthreads();
  red[tid] = l2;
  __syncthreads();
  for (int s = 128; s > 0; s >>= 1) { if (tid < s) red[tid] += red[tid + s]; __syncthreads(); }
  if (tid == 0) {
    const float s2c = red[0];
    const float e = __expf(T - vmax);
    const float g1 = fb ? 0.0f : s1g;
    const float g2 = fb ? 0.0f : s2g;
    const float denom = g1 + s1c + (float)nT * e;
    const float num = g2 + s2c + (float)nT * e * T;
    out[b] = num / denom;
  }
}

// ---------------------------------------------------------------------------
extern "C" void kernel_launch(void* const* d_in, const int* in_sizes, int n_in,
                              void* d_out, int out_size, void* d_ws, size_t ws_size,
                              hipStream_t stream) {
  const float* l_tok = (const float*)d_in[0];
  const float* p_tok = (const float*)d_in[1];
  const void* l_pad = d_in[2];
  const void* p_pad = d_in[3];
  const float* Wl = (const float*)d_in[4];
  const float* bl = (const float*)d_in[5];
  const float* Wp = (const float*)d_in[6];
  const float* bp = (const float*)d_in[7];
  const float* W1 = (const float*)d_in[8];
  const float* b1 = (const float*)d_in[9];
  const float* W2 = (const float*)d_in[10];
  const float* b2 = (const float*)d_in[11];
  const float* W3 = (const float*)d_in[12];
  const float* b3 = (const float*)d_in[13];

  float* ws = (float*)d_ws;
  float* wl_ = ws;                    // [2,96,256]
  float* wp_ = ws + 49152;            // [2,768,256]
  float* wA = ws + 442368;            // A1 [2,96,128]
  float* wB = ws + 466944;            // B1 [2,768,128]
  float* wLog = ws + 663552;          // logits [2,73728]
  unsigned char* lmask = (unsigned char*)(ws + 811008);
  unsigned char* pmask = lmask + NB * LL;
  unsigned short* W1xf = (unsigned short*)(ws + 811520);  // 65536 u16
  unsigned short* W2f = (unsigned short*)(ws + 844288);   // 16384 u16
  unsigned* hist = (unsigned*)(ws + 852480);              // [2][NBIN] u32
  unsigned* ctrl = (unsigned*)(ws + 852480 + NB * NBIN);  // 16 u32
  float* cand = ws + 852480 + NB * NBIN + 16;             // [2][CAP]

  // zero hist + ctrl each launch (graph-safe)
  hipMemsetAsync((void*)hist, 0, (NB * NBIN + 16) * sizeof(unsigned), stream);

  prep_kernel<<<321 + NB * (LL + LP) / 16, 256, 0, stream>>>(
      l_pad, p_pad, lmask, pmask, W1, W2, W1xf, W2f,
      l_tok, p_tok, Wl, bl, Wp, bp, b1, wl_, wp_, wA, wB);

  dim3 grid(LP / PB, LL / LB, NB);
  pair2_kernel<<<grid, 256, 0, stream>>>(wl_, wp_, wA, wB, W1xf, W2f,
                                         b2, W3, b3, lmask, pmask, wLog);
  hist_kernel<<<dim3(32, NB), 256, 0, stream>>>(wLog, hist);
  findbin_kernel<<<1, 256, 0, stream>>>(hist, ctrl);
  sums_kernel<<<dim3(32, NB), 256, 0, stream>>>(wLog, ctrl, cand);
  final_kernel<<<NB, 256, 0, stream>>>(wLog, ctrl, cand, (float*)d_out);
}

// Round 6
// 161.331 us; speedup vs baseline: 2.2487x; 1.2234x over previous
//
#include <hip/hip_runtime.h>
#include <hip/hip_bf16.h>
#include <math.h>

#define LL 96
#define LP 768
#define BD 256
#define HD 128
#define NB 2
#define NEGV (-20.0f)
#define LB 8    // ligands per block
#define PB 16   // proteins per block

#define NBIN 4096    // top-12-bit key histogram
#define BSHIFT 20
#define CAP 8192     // candidate buffer per batch
#define NLOG (LL * LP)

typedef __attribute__((ext_vector_type(4))) float f32x4;
typedef __attribute__((ext_vector_type(4))) unsigned int u32x4;
typedef __attribute__((ext_vector_type(8))) short s16x8;

// Abramowitz-Stegun 7.1.26 erf, |err| <= 1.5e-7 absolute. ~14 VALU ops.
__device__ __forceinline__ float gelu_fast(float x) {
  float ax = fabsf(x) * 0.70710678118654752f;
  float t = 1.0f / fmaf(0.3275911f, ax, 1.0f);
  float poly = t * fmaf(t, fmaf(t, fmaf(t, fmaf(t, 1.061405429f, -1.453152027f),
                                        1.421413741f), -0.284496736f), 0.254829592f);
  float e = __expf(-ax * ax);
  float erfax = fmaf(-poly, e, 1.0f);
  float erfx = copysignf(erfax, x);
  return 0.5f * x * (1.0f + erfx);
}

__device__ __forceinline__ f32x4 mfma16(s16x8 a, s16x8 b, f32x4 c) {
  return __builtin_amdgcn_mfma_f32_16x16x32_bf16(a, b, c, 0, 0, 0);
}

__device__ __forceinline__ unsigned pack_bf16(float a, float b) {
  float2 t; t.x = a; t.y = b;
  __hip_bfloat162 h = __float22bfloat162_rn(t);
  return *reinterpret_cast<unsigned*>(&h);
}

__device__ __forceinline__ s16x8 as_s16x8(u32x4 v) {
  return __builtin_bit_cast(s16x8, v);
}

__device__ __forceinline__ unsigned short bfbits(float x) {
  __hip_bfloat16 h = __float2bfloat16(x);
  return *reinterpret_cast<unsigned short*>(&h);
}

__device__ __forceinline__ unsigned int fkey(float f) {
  unsigned int u = __float_as_uint(f);
  return u ^ ((u >> 31) ? 0xFFFFFFFFu : 0x80000000u);
}
__device__ __forceinline__ float finv(unsigned int k) {
  unsigned int u = k ^ ((k >> 31) ? 0x80000000u : 0xFFFFFFFFu);
  return __uint_as_float(u);
}

// ctrl layout (u32): [0,1]=ubkey (>= max)  [2,3]=binB count  [4,5]=B  [6,7]=G
//                    [8,9]=s1(float) [10,11]=s2(float) [12..15]=pad

// ---- fused prep: pad decode + hist/ctrl zero | weight swizzle | projections
__global__ __launch_bounds__(256) void prep_kernel(
    const void* lp, const void* pp, unsigned char* lmask, unsigned char* pmask,
    const float* __restrict__ W1, const float* __restrict__ W2,
    unsigned short* __restrict__ W1xf, unsigned short* __restrict__ W2f,
    const float* __restrict__ l_tok, const float* __restrict__ p_tok,
    const float* __restrict__ Wl, const float* __restrict__ bl,
    const float* __restrict__ Wp, const float* __restrict__ bp,
    const float* __restrict__ b1,
    float* __restrict__ wl_, float* __restrict__ wp_,
    float* __restrict__ wA, float* __restrict__ wB,
    unsigned* __restrict__ zero_base) {
  __shared__ float Xs[16 * 256];
  __shared__ float Ys[16 * 256];
  __shared__ int bad;
  const int tid = threadIdx.x;
  if (blockIdx.x == 0) {
    // zero hist + ctrl (graph-safe re-init each launch)
    for (int i = tid; i < NB * NBIN + 16; i += 256) zero_base[i] = 0u;
    if (tid == 0) bad = 0;
    __syncthreads();
    const unsigned int* li = (const unsigned int*)lp;
    const unsigned int* pi = (const unsigned int*)pp;
    for (int i = tid; i < NB * LL; i += 256) if (li[i] > 1u) atomicOr(&bad, 1);
    for (int i = tid; i < NB * LP; i += 256) if (pi[i] > 1u) atomicOr(&bad, 1);
    __syncthreads();
    const bool asInt = (bad == 0);
    const unsigned char* lb = (const unsigned char*)lp;
    const unsigned char* pb = (const unsigned char*)pp;
    for (int i = tid; i < NB * LL; i += 256)
      lmask[i] = asInt ? (unsigned char)(li[i] != 0u) : (unsigned char)(lb[i] != 0);
    for (int i = tid; i < NB * LP; i += 256)
      pmask[i] = asInt ? (unsigned char)(pi[i] != 0u) : (unsigned char)(pb[i] != 0);
    return;
  }
  if (blockIdx.x < 321) {
    int idx = (blockIdx.x - 1) * 256 + tid;
    if (idx < 65536) {
      int j = idx & 7, ln = (idx >> 3) & 63;
      int rest = idx >> 9;
      int mt = rest & 7, kt = (rest >> 3) & 1, cc = rest >> 4;
      int row = 512 + cc * 64 + kt * 32 + ((ln >> 4) << 3) + j;
      int col = mt * 16 + (ln & 15);
      W1xf[idx] = bfbits(W1[row * HD + col]);
    } else if (idx < 65536 + 16384) {
      int e = idx - 65536;
      int j = e & 7, ln = (e >> 3) & 63, mt = (e >> 9) & 7, kt = e >> 12;
      int row = kt * 32 + ((ln >> 4) << 3) + j;
      int col = mt * 16 + (ln & 15);
      W2f[e] = bfbits(W2[row * HD + col]);
    }
    return;
  }
  // ---- projection chain: X@W+b -> Y1; Y1@W1part(+b1) -> Y2 ----
  const int pblk = blockIdx.x - 321;
  const bool isL = pblk < (NB * LL / 16);
  const int blk = isL ? pblk : (pblk - NB * LL / 16);
  const int r0 = blk * 16;
  const float* X = isL ? l_tok : p_tok;
  const float* W = isL ? Wl : Wp;
  const float* bias = isL ? bl : bp;
  float* Y1 = isL ? wl_ : wp_;
  float* Y2 = isL ? wA : wB;
  const float* W1p = isL ? W1 : (W1 + 256 * HD);

#pragma unroll
  for (int q = 0; q < 16; ++q)
    Xs[tid + q * 256] = X[(size_t)r0 * 256 + tid + q * 256];
  __syncthreads();
  {
    const int cc = tid;
    float bv = bias[cc];
    float acc[16];
#pragma unroll
    for (int i = 0; i < 16; ++i) acc[i] = bv;
    for (int k4 = 0; k4 < 256; k4 += 4) {
      float wv[4];
#pragma unroll
      for (int q = 0; q < 4; ++q) wv[q] = W[(size_t)(k4 + q) * 256 + cc];
#pragma unroll
      for (int i = 0; i < 16; ++i) {
        f32x4 xv = *(const f32x4*)&Xs[i * 256 + k4];
#pragma unroll
        for (int q = 0; q < 4; ++q) acc[i] = fmaf(xv[q], wv[q], acc[i]);
      }
    }
#pragma unroll
    for (int i = 0; i < 16; ++i) {
      Y1[(size_t)(r0 + i) * 256 + cc] = acc[i];
      Ys[i * 256 + cc] = acc[i];
    }
  }
  __syncthreads();
  {
    const int c2 = tid & 127;
    const int half = tid >> 7;
    float bv = isL ? b1[c2] : 0.0f;
    float acc[8];
#pragma unroll
    for (int i = 0; i < 8; ++i) acc[i] = bv;
    for (int k4 = 0; k4 < 256; k4 += 4) {
      float wv[4];
#pragma unroll
      for (int q = 0; q < 4; ++q) wv[q] = W1p[(size_t)(k4 + q) * HD + c2];
#pragma unroll
      for (int i = 0; i < 8; ++i) {
        f32x4 yv = *(const f32x4*)&Ys[(half * 8 + i) * 256 + k4];
#pragma unroll
        for (int q = 0; q < 4; ++q) acc[i] = fmaf(yv[q], wv[q], acc[i]);
      }
    }
#pragma unroll
    for (int i = 0; i < 8; ++i)
      Y2[(size_t)(r0 + half * 8 + i) * HD + c2] = acc[i];
  }
}

// ---------------- MFMA pair kernel: in-register B-fragment build ------------
// B-frag for tile ntg needs only lt[ntg][kslice] (wave-uniform -> broadcast)
// and pt[lane&15][kslice]; built per-lane in VGPRs, fed straight to MFMA.
// No F LDS round-trip; 1 barrier per d-chunk. H transpose still via LDS (U).
__global__ __launch_bounds__(256, 3) void pair2_kernel(
    const float* __restrict__ lbuf, const float* __restrict__ pbuf,
    const float* __restrict__ A1, const float* __restrict__ B1,
    const unsigned short* __restrict__ W1xf, const unsigned short* __restrict__ W2f,
    const float* __restrict__ b2, const float* __restrict__ W3,
    const float* __restrict__ b3, const unsigned char* __restrict__ lmask,
    const unsigned char* __restrict__ pmask, float* __restrict__ logits) {
  // U: main loop = ltpt double buffer (2 x 1632 floats); epilogue = H frags (8192)
  __shared__ float U[8192];
  __shared__ float b2s[HD];
  __shared__ float w3s[HD];
  __shared__ float redbuf[128];

  const int tid = threadIdx.x;
  const int lane = tid & 63;
  const int w = tid >> 6;
  const int g = lane >> 4;
  const int c = lane & 15;
  const int wm = w >> 1;  // hid half
  const int wn = w & 1;   // ligand half
  const int bb = blockIdx.z;
  const int i0 = blockIdx.y * LB;
  const int j0 = blockIdx.x * PB;

  if (tid < 128) b2s[tid] = b2[tid];
  else w3s[tid - 128] = W3[tid - 128];

  float* lt0 = U;         // buffer 0: rows 0..7 = l, 8..23 = p, stride 68
  float* lt1 = U + 1632;  // buffer 1

  const int srow = tid >> 4, sq = tid & 15;
  const int srow2 = (tid + 256) >> 4;

  auto gaddr = [&](int row, int q, int c4) -> const float* {
    return (row < 8)
        ? &lbuf[(size_t)(bb * LL + i0 + row) * BD + c4 * 64 + q * 4]
        : &pbuf[(size_t)(bb * LP + j0 + (row - 8)) * BD + c4 * 64 + q * 4];
  };

  {
    f32x4 r0 = {}, r1 = {};
    if (tid < 384) r0 = *(const f32x4*)gaddr(srow, sq, 0);
    if (tid < 128) r1 = *(const f32x4*)gaddr(srow2, sq, 0);
    if (tid < 384) *(f32x4*)&lt0[srow * 68 + sq * 4] = r0;
    if (tid < 128) *(f32x4*)&lt0[srow2 * 68 + sq * 4] = r1;
  }
  __syncthreads();

  f32x4 acc1[4][4];
#pragma unroll
  for (int m = 0; m < 4; ++m)
#pragma unroll
    for (int n = 0; n < 4; ++n) acc1[m][n] = (f32x4)0.0f;

  for (int c4 = 0; c4 < 4; ++c4) {
    float* cur = (c4 & 1) ? lt1 : lt0;
    float* nxt = (c4 & 1) ? lt0 : lt1;

    // issue next chunk's global loads early (hidden under compute)
    f32x4 r0 = {}, r1 = {};
    if (c4 < 3) {
      if (tid < 384) r0 = *(const f32x4*)gaddr(srow, sq, c4 + 1);
      if (tid < 128) r1 = *(const f32x4*)gaddr(srow2, sq, c4 + 1);
    }

#pragma unroll
    for (int kt = 0; kt < 2; ++kt) {
      const int kc0 = kt * 32 + g * 8;
      // A-frags (pre-swizzled W1 columns) for both feature types
      s16x8 a0[4], a1[4];
#pragma unroll
      for (int m = 0; m < 4; ++m) {
        a0[m] = *(const s16x8*)(W1xf +
            ((size_t)((c4 * 2 + kt) * 8 + (wm * 4 + m)) * 64 + lane) * 8);
        a1[m] = *(const s16x8*)(W1xf +
            ((size_t)(((4 + c4) * 2 + kt) * 8 + (wm * 4 + m)) * 64 + lane) * 8);
      }
      const f32x4 p0 = *(const f32x4*)&cur[(8 + c) * 68 + kc0];
      const f32x4 p1 = *(const f32x4*)&cur[(8 + c) * 68 + kc0 + 4];
#pragma unroll
      for (int n = 0; n < 4; ++n) {
        const int ntg = wn * 4 + n;
        const f32x4 l0 = *(const f32x4*)&cur[ntg * 68 + kc0];   // broadcast
        const f32x4 l1 = *(const f32x4*)&cur[ntg * 68 + kc0 + 4];
        u32x4 bv;
        bv[0] = pack_bf16(l0[0] * p0[0], l0[1] * p0[1]);
        bv[1] = pack_bf16(l0[2] * p0[2], l0[3] * p0[3]);
        bv[2] = pack_bf16(l1[0] * p1[0], l1[1] * p1[1]);
        bv[3] = pack_bf16(l1[2] * p1[2], l1[3] * p1[3]);
        s16x8 bf0 = as_s16x8(bv);
#pragma unroll
        for (int m = 0; m < 4; ++m) acc1[m][n] = mfma16(a0[m], bf0, acc1[m][n]);
        bv[0] = pack_bf16(fabsf(l0[0] - p0[0]), fabsf(l0[1] - p0[1]));
        bv[1] = pack_bf16(fabsf(l0[2] - p0[2]), fabsf(l0[3] - p0[3]));
        bv[2] = pack_bf16(fabsf(l1[0] - p1[0]), fabsf(l1[1] - p1[1]));
        bv[3] = pack_bf16(fabsf(l1[2] - p1[2]), fabsf(l1[3] - p1[3]));
        s16x8 bf1 = as_s16x8(bv);
#pragma unroll
        for (int m = 0; m < 4; ++m) acc1[m][n] = mfma16(a1[m], bf1, acc1[m][n]);
      }
    }

    if (c4 < 3) {
      if (tid < 384) *(f32x4*)&nxt[srow * 68 + sq * 4] = r0;
      if (tid < 128) *(f32x4*)&nxt[srow2 * 68 + sq * 4] = r1;
    }
    __syncthreads();
  }
  // final barrier above: all ltpt reads done -> H may overlay U

  // epilogue layer1: h = gelu(D1 + A1 + B1); write H in layer2-B-frag order
  unsigned* Hdw = (unsigned*)U;
#pragma unroll
  for (int m = 0; m < 4; ++m) {
    const int hidM = wm * 4 + m;
    const int kt2 = (4 * hidM + g) >> 3;
    const int l2 = ((2 * hidM + (g >> 1)) & 3) * 16 + c;
    const int jd = (g & 1) * 2;
#pragma unroll
    for (int n = 0; n < 4; ++n) {
      const int ntg = wn * 4 + n;
      f32x4 a1v = *(const f32x4*)&A1[(size_t)(bb * LL + i0 + ntg) * HD + hidM * 16 + g * 4];
      f32x4 b1v = *(const f32x4*)&B1[(size_t)(bb * LP + j0 + c) * HD + hidM * 16 + g * 4];
      float h0 = gelu_fast(acc1[m][n][0] + a1v[0] + b1v[0]);
      float h1 = gelu_fast(acc1[m][n][1] + a1v[1] + b1v[1]);
      float h2 = gelu_fast(acc1[m][n][2] + a1v[2] + b1v[2]);
      float h3 = gelu_fast(acc1[m][n][3] + a1v[3] + b1v[3]);
      int base = ((kt2 * 8 + ntg) * 64 + l2) * 4 + jd;
      Hdw[base] = pack_bf16(h0, h1);
      Hdw[base + 1] = pack_bf16(h2, h3);
    }
  }
  __syncthreads();

  // layer 2: D2 = W2^T @ H
  f32x4 acc2[4][4];
#pragma unroll
  for (int m = 0; m < 4; ++m)
#pragma unroll
    for (int n = 0; n < 4; ++n) acc2[m][n] = (f32x4)0.0f;

  const unsigned short* Hush = (const unsigned short*)U;
#pragma unroll
  for (int kt = 0; kt < 4; ++kt) {
    s16x8 a2[4];
#pragma unroll
    for (int m = 0; m < 4; ++m)
      a2[m] = *(const s16x8*)(W2f + (size_t)((kt * 8 + (wm * 4 + m)) * 64 + lane) * 8);
#pragma unroll
    for (int n = 0; n < 4; ++n) {
      s16x8 bf = *((const s16x8*)Hush + ((kt * 8 + (wn * 4 + n)) * 64 + lane));
#pragma unroll
      for (int m = 0; m < 4; ++m) acc2[m][n] = mfma16(a2[m], bf, acc2[m][n]);
    }
  }

  // layer3: gelu + dot W3, reduce over hid
  float partial[4] = {0.0f, 0.0f, 0.0f, 0.0f};
#pragma unroll
  for (int m = 0; m < 4; ++m) {
    const int hb = (wm * 4 + m) * 16 + g * 4;
    f32x4 b2v = *(const f32x4*)&b2s[hb];
    f32x4 w3v = *(const f32x4*)&w3s[hb];
#pragma unroll
    for (int n = 0; n < 4; ++n) {
#pragma unroll
      for (int r = 0; r < 4; ++r)
        partial[n] = fmaf(gelu_fast(acc2[m][n][r] + b2v[r]), w3v[r], partial[n]);
    }
  }
#pragma unroll
  for (int n = 0; n < 4; ++n) {
    partial[n] += __shfl_xor(partial[n], 16, 64);
    partial[n] += __shfl_xor(partial[n], 32, 64);
  }
  if (wm == 0 && g == 0) {
#pragma unroll
    for (int n = 0; n < 4; ++n) redbuf[wn * 64 + n * 16 + c] = partial[n];
  }
  __syncthreads();
  if (wm == 1 && g == 0) {
    const float bb3 = b3[0];
#pragma unroll
    for (int n = 0; n < 4; ++n) {
      const int ntg = wn * 4 + n;
      float v = partial[n] + redbuf[wn * 64 + n * 16 + c] + bb3;
      if (isnan(v)) v = 0.0f;
      else if (isinf(v)) v = (v > 0.0f) ? 20.0f : NEGV;
      const int i = i0 + ntg, j = j0 + c;
      if (lmask[bb * LL + i] || pmask[bb * LP + j]) v = NEGV;
      logits[(size_t)bb * NLOG + i * LP + j] = v;
    }
  }
}

// ---------------- per-block LDS histogram over logit keys -------------------
__global__ __launch_bounds__(256) void hist_kernel(const float* __restrict__ logits,
                                                   unsigned* __restrict__ hist) {
  __shared__ unsigned lh[NBIN];
  const int b = blockIdx.y;
  const int tid = threadIdx.x;
  for (int i = tid; i < NBIN; i += 256) lh[i] = 0u;
  __syncthreads();
  const float* data = logits + (size_t)b * NLOG;
  const int stride = gridDim.x * 256;
  for (int i = blockIdx.x * 256 + tid; i < NLOG; i += stride)
    atomicAdd(&lh[fkey(data[i]) >> BSHIFT], 1u);
  __syncthreads();
  unsigned* gh = hist + b * NBIN;
  for (int i = tid; i < NBIN; i += 256) {
    unsigned v = lh[i];
    if (v) atomicAdd(&gh[i], v);
  }
}

// ------- find bin of the 100th largest + upper bound on max (no atomics) ----
__global__ __launch_bounds__(256) void findbin_kernel(const unsigned* __restrict__ hist,
                                                      unsigned* __restrict__ ctrl) {
  __shared__ unsigned csum[256];
  __shared__ unsigned suf[256];
  __shared__ unsigned topb[256];
  const int tid = threadIdx.x;
  for (int b = 0; b < NB; ++b) {
    const unsigned* h = hist + b * NBIN;
    const int base = tid * (NBIN / 256);
    unsigned s = 0;
    int top = -1;
    for (int i = 0; i < NBIN / 256; ++i) {
      unsigned cnt = h[base + i];
      s += cnt;
      if (cnt) top = base + i;
    }
    csum[tid] = s;
    topb[tid] = (unsigned)(top + 1);
    __syncthreads();
    if (tid == 0) {
      unsigned a = 0;
      for (int t = 255; t >= 0; --t) { suf[t] = a; a += csum[t]; }
      unsigned mt = 0;
      for (int t = 0; t < 256; ++t) mt = max(mt, topb[t]);
      ctrl[b] = ((mt - 1u) << BSHIFT) | ((1u << BSHIFT) - 1u);
    }
    __syncthreads();
    unsigned above = suf[tid];
    if (above < 100u && above + csum[tid] >= 100u) {
      unsigned a = above;
      for (int i = NBIN / 256 - 1; i >= 0; --i) {
        unsigned hc = h[base + i];
        if (a + hc >= 100u) { ctrl[4 + b] = base + i; ctrl[6 + b] = a; break; }
        a += hc;
      }
    }
    __syncthreads();
  }
}

// ---------------- parallel pass: sums above bin B + collect bin-B candidates
__global__ __launch_bounds__(256) void sums_kernel(const float* __restrict__ logits,
                                                   unsigned* __restrict__ ctrl,
                                                   float* __restrict__ cand) {
  const int b = blockIdx.y;
  const float* data = logits + (size_t)b * NLOG;
  const unsigned B = ctrl[4 + b];
  const float vmax = finv(ctrl[b]);
  float* s1 = (float*)&ctrl[8 + b];
  float* s2 = (float*)&ctrl[10 + b];
  const int stride = gridDim.x * 256;
  float l1 = 0.0f, l2 = 0.0f;
  for (int i = blockIdx.x * 256 + threadIdx.x; i < NLOG; i += stride) {
    float v = data[i];
    unsigned kb = fkey(v) >> BSHIFT;
    if (kb > B) {
      float e = __expf(v - vmax);
      l1 += e;
      l2 = fmaf(e, v, l2);
    } else if (kb == B) {
      unsigned pos = atomicAdd(&ctrl[2 + b], 1u);
      if (pos < CAP) cand[(size_t)b * CAP + pos] = v;
    }
  }
  if (l1 != 0.0f) { atomicAdd(s1, l1); atomicAdd(s2, l2); }
}

// ---------------- exact select among candidates + combine -------------------
__global__ __launch_bounds__(256) void final_kernel(const float* __restrict__ logits,
                                                    const unsigned* __restrict__ ctrl,
                                                    const float* __restrict__ cand,
                                                    float* __restrict__ out) {
  __shared__ float cv[CAP];
  __shared__ unsigned h8[256];
  __shared__ float red[256];
  __shared__ unsigned sP, sN;
  const int b = blockIdx.x;
  const int tid = threadIdx.x;
  const unsigned count = ctrl[2 + b];
  const float vmax = finv(ctrl[b]);
  const unsigned G = ctrl[6 + b];
  const float s1g = ((const float*)ctrl)[8 + b];
  const float s2g = ((const float*)ctrl)[10 + b];
  const float* data = logits + (size_t)b * NLOG;
  const bool fb = count > CAP;  // degenerate fallback: full-array select
  const unsigned C = fb ? 0u : count;

  if (!fb) for (int i = tid; i < (int)C; i += 256) cv[i] = cand[(size_t)b * CAP + i];
  if (tid == 0) { sP = 0u; sN = fb ? 100u : (100u - G); }
  __syncthreads();

  for (int sh = 24; sh >= 0; sh -= 8) {
    h8[tid] = 0u;
    __syncthreads();
    const unsigned prefix = sP;
    const unsigned maskhi = (sh == 24) ? 0u : (0xFFFFFFFFu << (sh + 8));
    if (!fb) {
      for (int i = tid; i < (int)C; i += 256) {
        unsigned k = fkey(cv[i]);
        if ((k & maskhi) == (prefix & maskhi)) atomicAdd(&h8[(k >> sh) & 255], 1u);
      }
    } else {
      for (int i = tid; i < NLOG; i += 256) {
        unsigned k = fkey(data[i]);
        if ((k & maskhi) == (prefix & maskhi)) atomicAdd(&h8[(k >> sh) & 255], 1u);
      }
    }
    __syncthreads();
    if (tid == 0) {
      unsigned need = sN, cum = 0u;
      int d = 0;
      for (d = 255; d >= 0; --d) { cum += h8[d]; if (cum >= need) break; }
      sN = need - (cum - h8[d]);
      sP = prefix | ((unsigned)d << sh);
    }
    __syncthreads();
  }
  const unsigned Tkey = sP;
  const unsigned nT = sN;
  const float T = finv(Tkey);

  float l1 = 0.0f, l2 = 0.0f;
  if (!fb) {
    for (int i = tid; i < (int)C; i += 256) {
      float v = cv[i];
      if (fkey(v) > Tkey) { float e = __expf(v - vmax); l1 += e; l2 = fmaf(e, v, l2); }
    }
  } else {
    for (int i = tid; i < NLOG; i += 256) {
      float v = data[i];
      if (fkey(v) > Tkey) { float e = __expf(v - vmax); l1 += e; l2 = fmaf(e, v, l2); }
    }
  }
  red[tid] = l1;
  __syncthreads();
  for (int s = 128; s > 0; s >>= 1) { if (tid < s) red[tid] += red[tid + s]; __syncthreads(); }
  const float s1c = red[0];
  __syncthreads();
  red[tid] = l2;
  __syncthreads();
  for (int s = 128; s > 0; s >>= 1) { if (tid < s) red[tid] += red[tid + s]; __syncthreads(); }
  if (tid == 0) {
    const float s2c = red[0];
    const float e = __expf(T - vmax);
    const float g1 = fb ? 0.0f : s1g;
    const float g2 = fb ? 0.0f : s2g;
    const float denom = g1 + s1c + (float)nT * e;
    const float num = g2 + s2c + (float)nT * e * T;
    out[b] = num / denom;
  }
}

// ---------------------------------------------------------------------------
extern "C" void kernel_launch(void* const* d_in, const int* in_sizes, int n_in,
                              void* d_out, int out_size, void* d_ws, size_t ws_size,
                              hipStream_t stream) {
  const float* l_tok = (const float*)d_in[0];
  const float* p_tok = (const float*)d_in[1];
  const void* l_pad = d_in[2];
  const void* p_pad = d_in[3];
  const float* Wl = (const float*)d_in[4];
  const float* bl = (const float*)d_in[5];
  const float* Wp = (const float*)d_in[6];
  const float* bp = (const float*)d_in[7];
  const float* W1 = (const float*)d_in[8];
  const float* b1 = (const float*)d_in[9];
  const float* W2 = (const float*)d_in[10];
  const float* b2 = (const float*)d_in[11];
  const float* W3 = (const float*)d_in[12];
  const float* b3 = (const float*)d_in[13];

  float* ws = (float*)d_ws;
  float* wl_ = ws;                    // [2,96,256]
  float* wp_ = ws + 49152;            // [2,768,256]
  float* wA = ws + 442368;            // A1 [2,96,128]
  float* wB = ws + 466944;            // B1 [2,768,128]
  float* wLog = ws + 663552;          // logits [2,73728]
  unsigned char* lmask = (unsigned char*)(ws + 811008);
  unsigned char* pmask = lmask + NB * LL;
  unsigned short* W1xf = (unsigned short*)(ws + 811520);  // 65536 u16
  unsigned short* W2f = (unsigned short*)(ws + 844288);   // 16384 u16
  unsigned* hist = (unsigned*)(ws + 852480);              // [2][NBIN] u32
  unsigned* ctrl = (unsigned*)(ws + 852480 + NB * NBIN);  // 16 u32
  float* cand = ws + 852480 + NB * NBIN + 16;             // [2][CAP]

  prep_kernel<<<321 + NB * (LL + LP) / 16, 256, 0, stream>>>(
      l_pad, p_pad, lmask, pmask, W1, W2, W1xf, W2f,
      l_tok, p_tok, Wl, bl, Wp, bp, b1, wl_, wp_, wA, wB, hist);

  dim3 grid(LP / PB, LL / LB, NB);
  pair2_kernel<<<grid, 256, 0, stream>>>(wl_, wp_, wA, wB, W1xf, W2f,
                                         b2, W3, b3, lmask, pmask, wLog);
  hist_kernel<<<dim3(32, NB), 256, 0, stream>>>(wLog, hist);
  findbin_kernel<<<1, 256, 0, stream>>>(hist, ctrl);
  sums_kernel<<<dim3(32, NB), 256, 0, stream>>>(wLog, ctrl, cand);
  final_kernel<<<NB, 256, 0, stream>>>(wLog, ctrl, cand, (float*)d_out);
}